// Round 9
// baseline (1330.463 us; speedup 1.0000x reference)
//
#include <hip/hip_runtime.h>
#include <hip/hip_bf16.h>
#include <hip/hip_fp16.h>

// Problem constants (match reference)
constexpr int N   = 50000;
constexpr int R   = 51;
constexpr int E   = 16;
constexpr int C   = 8;
constexpr int B   = 40;
constexpr int NNZ = 1600000;
constexpr int RN  = R * N;            // 2550000 W1 rows

// Column-bucket sort: 1024 cols/bucket -> sequential W1 window per block
constexpr int CSH = 10;
constexpr int CB  = (RN + (1 << CSH) - 1) >> CSH;   // 2491 buckets
constexpr int CMASK22 = (1 << 22) - 1;

constexpr int CBLK   = 784;
constexpr int CCHUNK = (NNZ + CBLK - 1) / CBLK;     // 2041
constexpr int SBLK   = 128;
constexpr int SCHUNK = (NNZ + SBLK - 1) / SBLK;     // 12500

// ---------------------------------------------------------------------------
// K1: W1 = comps1(R,B) @ bases1(B,N*E), fp16-packed (row = 16 halfs = 32B)
// ---------------------------------------------------------------------------
__global__ __launch_bounds__(256) void w1_gemm_kernel(
    const float* __restrict__ comps1, const float* __restrict__ bases1,
    unsigned* __restrict__ W1u) {
  constexpr int NC2 = N * E / 2;  // 400000 pair-columns
  int j = blockIdx.x * 256 + threadIdx.x;
  if (j >= NC2) return;
  const float2* b2 = reinterpret_cast<const float2*>(bases1);
  float2 col[B];
#pragma unroll
  for (int b = 0; b < B; ++b) col[b] = b2[b * NC2 + j];
#pragma unroll 1
  for (int r = 0; r < R; ++r) {
    float ax = 0.f, ay = 0.f;
#pragma unroll
    for (int b = 0; b < B; ++b) {
      float cc = comps1[r * B + b];   // block-uniform -> scalar loads
      ax = fmaf(cc, col[b].x, ax);
      ay = fmaf(cc, col[b].y, ay);
    }
    unsigned lo = __half_as_ushort(__float2half(ax));
    unsigned hi = __half_as_ushort(__float2half(ay));
    W1u[r * NC2 + j] = (hi << 16) | lo;
  }
}

// ---------------------------------------------------------------------------
// K2: histogram over col buckets (col = p*N+o, bucket = col>>10)
// ---------------------------------------------------------------------------
__global__ __launch_bounds__(256) void count_kernel(
    const int* __restrict__ cols, int* __restrict__ gcount) {
  __shared__ int hist[CB];
  for (int i = threadIdx.x; i < CB; i += 256) hist[i] = 0;
  __syncthreads();
  int lo = blockIdx.x * CCHUNK;
  int hi = lo + CCHUNK < NNZ ? lo + CCHUNK : NNZ;
  for (int i = lo + threadIdx.x; i < hi; i += 256)
    atomicAdd(&hist[(unsigned)cols[i] >> CSH], 1);
  __syncthreads();
  for (int i = threadIdx.x; i < CB; i += 256)
    if (hist[i]) atomicAdd(&gcount[i], hist[i]);
}

// ---------------------------------------------------------------------------
// K3: scan of CB bucket counts -> gstart[CB+1], gcursor[CB]
// ---------------------------------------------------------------------------
__global__ __launch_bounds__(1024) void scan_kernel(
    const int* __restrict__ gcount, int* __restrict__ gstart,
    int* __restrict__ gcursor) {
  __shared__ int buf[1024];
  constexpr int CH = (CB + 1023) / 1024;  // 3
  int t = threadIdx.x;
  int lo = t * CH;
  int hi = lo + CH < CB ? lo + CH : CB;
  int s = 0;
  for (int i = lo; i < hi; ++i) s += gcount[i];
  buf[t] = s;
  __syncthreads();
  for (int d = 1; d < 1024; d <<= 1) {
    int v = (t >= d) ? buf[t - d] : 0;
    __syncthreads();
    buf[t] += v;
    __syncthreads();
  }
  int run = (t > 0) ? buf[t - 1] : 0;
  for (int i = lo; i < hi; ++i) {
    gstart[i] = run;
    gcursor[i] = run;
    run += gcount[i];
  }
  if (t == 1023) gstart[CB] = buf[1023];  // = NNZ
}

// ---------------------------------------------------------------------------
// K4: scatter into col-bucket-grouped packed records (8B):
//     w0 = (s&1023)<<22 | col ; w1 = (v_bits & ~63) | (s>>10)
//     (v loses 6 low mantissa bits: rel err 2^-18, negligible)
// ---------------------------------------------------------------------------
__global__ __launch_bounds__(1024) void scatter_kernel(
    const int* __restrict__ rows, const int* __restrict__ cols,
    const float* __restrict__ vals, int* __restrict__ gcursor,
    int2* __restrict__ packed) {
  __shared__ int hist[CB];
  __shared__ int base[CB];
  for (int i = threadIdx.x; i < CB; i += 1024) hist[i] = 0;
  __syncthreads();
  int lo = blockIdx.x * SCHUNK;
  int hi = lo + SCHUNK < NNZ ? lo + SCHUNK : NNZ;
  for (int i = lo + threadIdx.x; i < hi; i += 1024)
    atomicAdd(&hist[(unsigned)cols[i] >> CSH], 1);
  __syncthreads();
  for (int i = threadIdx.x; i < CB; i += 1024) {
    int c = hist[i];
    base[i] = c ? atomicAdd(&gcursor[i], c) : 0;
  }
  __syncthreads();
  for (int i = threadIdx.x; i < CB; i += 1024) hist[i] = 0;  // reuse as cursor
  __syncthreads();
  for (int i = lo + threadIdx.x; i < hi; i += 1024) {
    unsigned col = (unsigned)cols[i];
    int b = col >> CSH;
    unsigned s = (unsigned)rows[i];
    int pos = base[b] + atomicAdd(&hist[b], 1);
    unsigned w0 = ((s & 1023u) << 22) | col;
    unsigned w1 = (__float_as_uint(vals[i]) & ~63u) | (s >> 10);
    packed[pos] = make_int2((int)w0, (int)w1);
  }
}

// ---------------------------------------------------------------------------
// K5: W2 = comps2 @ bases2 (tiny), layout [p][e*8+c] fp32
// ---------------------------------------------------------------------------
__global__ void w2_gemm_kernel(const float* __restrict__ comps2,
                               const float* __restrict__ bases2,
                               float* __restrict__ W2g) {
  int i = blockIdx.x * blockDim.x + threadIdx.x;
  if (i >= R * E * C) return;
  int r = i >> 7;
  int ec = i & 127;
  float acc = 0.f;
#pragma unroll
  for (int b = 0; b < B; ++b)
    acc = fmaf(comps2[r * B + b], bases2[b * 128 + ec], acc);
  W2g[i] = acc;
}

// ---------------------------------------------------------------------------
// K6: layer 1, col-sorted. Block = col bucket: stream 32KB W1 window -> LDS
//     (stride 9 to spread banks), then per edge: 8 LDS half2 reads, pk mul,
//     8 global_atomic_pk_add_f16 into h16 (1.6MB, L2-resident).
// ---------------------------------------------------------------------------
__global__ __launch_bounds__(256) void layer1_kernel(
    const unsigned* __restrict__ W1u, const int* __restrict__ gstart,
    const int2* __restrict__ packed, __half2* __restrict__ h16) {
  __shared__ unsigned wlds[1024 * 9];   // 36.9KB, row stride 9
  int bkt = blockIdx.x;
  int rowbase = bkt << CSH;
  int nw = (RN - rowbase) < 1024 ? (RN - rowbase) * 8 : 8192;
  const unsigned* src = W1u + (size_t)rowbase * 8;
  for (int i = threadIdx.x; i < nw; i += 256)
    wlds[(i >> 3) * 9 + (i & 7)] = src[i];
  __syncthreads();
  int lo = gstart[bkt], hi = gstart[bkt + 1];
  for (int e = lo + (int)threadIdx.x; e < hi; e += 256) {
    int2 r = packed[e];
    unsigned w0 = (unsigned)r.x, w1 = (unsigned)r.y;
    int col = (int)(w0 & CMASK22);
    int s = (int)((w0 >> 22) | ((w1 & 63u) << 10));
    float v = __uint_as_float(w1 & ~63u);
    __half2 v2 = __float2half2_rn(v);
    int lrow = col - rowbase;
    const unsigned* wr = &wlds[lrow * 9];
    __half2* dst = h16 + (size_t)s * 8;
#pragma unroll
    for (int k = 0; k < 8; ++k) {
      __half2 wv = *reinterpret_cast<const __half2*>(&wr[k]);
      (void)unsafeAtomicAdd(dst + k, __hmul2(wv, v2));
    }
  }
}

// ---------------------------------------------------------------------------
// K7: h = relu(h16 + bias1) -> fp32 (3.2MB)
// ---------------------------------------------------------------------------
__global__ __launch_bounds__(256) void relu_kernel(
    const unsigned* __restrict__ h16u, const float* __restrict__ bias1,
    float* __restrict__ h) {
  int i = blockIdx.x * 256 + threadIdx.x;   // one per 8 elems
  if (i >= N * E / 8) return;
  uint4 raw = reinterpret_cast<const uint4*>(h16u)[i];
  int ebase = (i & 1) * 8;
  float4 o0, o1;
  float2 f;
  f = __half22float2(*reinterpret_cast<__half2*>(&raw.x));
  o0.x = fmaxf(f.x + bias1[ebase + 0], 0.f);
  o0.y = fmaxf(f.y + bias1[ebase + 1], 0.f);
  f = __half22float2(*reinterpret_cast<__half2*>(&raw.y));
  o0.z = fmaxf(f.x + bias1[ebase + 2], 0.f);
  o0.w = fmaxf(f.y + bias1[ebase + 3], 0.f);
  f = __half22float2(*reinterpret_cast<__half2*>(&raw.z));
  o1.x = fmaxf(f.x + bias1[ebase + 4], 0.f);
  o1.y = fmaxf(f.y + bias1[ebase + 5], 0.f);
  f = __half22float2(*reinterpret_cast<__half2*>(&raw.w));
  o1.z = fmaxf(f.x + bias1[ebase + 6], 0.f);
  o1.w = fmaxf(f.y + bias1[ebase + 7], 0.f);
  reinterpret_cast<float4*>(h)[i * 2 + 0] = o0;
  reinterpret_cast<float4*>(h)[i * 2 + 1] = o1;
}

// ---------------------------------------------------------------------------
// K8: layer 2, col-sorted. Block = col bucket: p is (near-)uniform -> stage
//     <=2 W2 rows in LDS. h[o] gathers from L2 (3.2MB). 4 pk atomics/edge
//     into out16 (0.8MB, L2-resident).
// ---------------------------------------------------------------------------
__global__ __launch_bounds__(256) void layer2_kernel(
    const float* __restrict__ h, const float* __restrict__ W2g,
    const int* __restrict__ gstart, const int2* __restrict__ packed,
    __half2* __restrict__ out16) {
  __shared__ float w2s[2][132];
  int bkt = blockIdx.x;
  int rowbase = bkt << CSH;
  int p0 = rowbase / N;
  int bound = (p0 + 1) * N;
  {
    int i = threadIdx.x;
    if (i < 128) {
      int e = i >> 3, c = i & 7;
      w2s[0][c * 16 + e] = W2g[p0 * 128 + i];
      if (p0 + 1 < R) w2s[1][c * 16 + e] = W2g[(p0 + 1) * 128 + i];
      else            w2s[1][c * 16 + e] = 0.f;
    }
  }
  __syncthreads();
  int lo = gstart[bkt], hi = gstart[bkt + 1];
  const float4* H4 = reinterpret_cast<const float4*>(h);
  for (int e = lo + (int)threadIdx.x; e < hi; e += 256) {
    int2 r = packed[e];
    unsigned w0 = (unsigned)r.x, w1 = (unsigned)r.y;
    int col = (int)(w0 & CMASK22);
    int s = (int)((w0 >> 22) | ((w1 & 63u) << 10));
    float v = __uint_as_float(w1 & ~63u);
    int pi = (col >= bound) ? 1 : 0;
    int o = col - p0 * N - pi * N;
    float4 h0 = H4[o * 4 + 0];
    float4 h1 = H4[o * 4 + 1];
    float4 h2 = H4[o * 4 + 2];
    float4 h3 = H4[o * 4 + 3];
    const float* wp = w2s[pi];
    float sum[8];
#pragma unroll
    for (int c = 0; c < 8; ++c) {
      const float4* wq = reinterpret_cast<const float4*>(wp + c * 16);
      float4 a = wq[0], bq = wq[1], cq = wq[2], dq = wq[3];
      sum[c] = v * (h0.x * a.x + h0.y * a.y + h0.z * a.z + h0.w * a.w
                  + h1.x * bq.x + h1.y * bq.y + h1.z * bq.z + h1.w * bq.w
                  + h2.x * cq.x + h2.y * cq.y + h2.z * cq.z + h2.w * cq.w
                  + h3.x * dq.x + h3.y * dq.y + h3.z * dq.z + h3.w * dq.w);
    }
    __half2* dst = out16 + (size_t)s * 4;
#pragma unroll
    for (int q = 0; q < 4; ++q)
      (void)unsafeAtomicAdd(dst + q, __floats2half2_rn(sum[2 * q], sum[2 * q + 1]));
  }
}

// ---------------------------------------------------------------------------
// K9: out = out16 + bias2 -> fp32
// ---------------------------------------------------------------------------
__global__ __launch_bounds__(256) void out_kernel(
    const unsigned* __restrict__ out16u, const float* __restrict__ bias2,
    float* __restrict__ out) {
  int i = blockIdx.x * 256 + threadIdx.x;   // one per node (8 outs)
  if (i >= N) return;
  uint4 raw = reinterpret_cast<const uint4*>(out16u)[i];
  float4 o0, o1;
  float2 f;
  f = __half22float2(*reinterpret_cast<__half2*>(&raw.x));
  o0.x = f.x + bias2[0]; o0.y = f.y + bias2[1];
  f = __half22float2(*reinterpret_cast<__half2*>(&raw.y));
  o0.z = f.x + bias2[2]; o0.w = f.y + bias2[3];
  f = __half22float2(*reinterpret_cast<__half2*>(&raw.z));
  o1.x = f.x + bias2[4]; o1.y = f.y + bias2[5];
  f = __half22float2(*reinterpret_cast<__half2*>(&raw.w));
  o1.z = f.x + bias2[6]; o1.w = f.y + bias2[7];
  reinterpret_cast<float4*>(out)[i * 2 + 0] = o0;
  reinterpret_cast<float4*>(out)[i * 2 + 1] = o1;
}

// ---------------------------------------------------------------------------
extern "C" void kernel_launch(void* const* d_in, const int* in_sizes, int n_in,
                              void* d_out, int out_size, void* d_ws, size_t ws_size,
                              hipStream_t stream) {
  const float* values  = (const float*)d_in[0];
  const float* comps1  = (const float*)d_in[1];
  const float* bases1  = (const float*)d_in[2];
  const float* comps2  = (const float*)d_in[3];
  const float* bases2  = (const float*)d_in[4];
  const float* bias1   = (const float*)d_in[5];
  const float* bias2   = (const float*)d_in[6];
  const int* hor_rows  = (const int*)d_in[7];
  const int* hor_cols  = (const int*)d_in[8];
  float* out = (float*)d_out;

  char* ws = (char*)d_ws;
  size_t off = 0;
  auto alloc = [&](size_t bytes) {
    void* p = ws + off;
    off += (bytes + 255) & ~size_t(255);
    return p;
  };
  unsigned* W1u    = (unsigned*)alloc((size_t)RN * 8 * 4);        // 81.6 MB fp16
  float*    h      = (float*)alloc((size_t)N * E * 4);            // 3.2 MB
  __half2*  h16    = (__half2*)alloc((size_t)N * E * 2);          // 1.6 MB
  __half2*  out16  = (__half2*)alloc((size_t)N * C * 2);          // 0.8 MB
  float*    W2g    = (float*)alloc((size_t)R * E * C * 4);
  int*      gcount = (int*)alloc((size_t)CB * 4);
  int*      gstart = (int*)alloc((size_t)(CB + 1) * 4);
  int*      gcursor= (int*)alloc((size_t)CB * 4);
  int2*     packed = (int2*)alloc((size_t)NNZ * 8);               // 12.8 MB
  (void)ws_size; (void)in_sizes; (void)n_in; (void)out_size;

  (void)hipMemsetAsync(gcount, 0, (size_t)CB * 4, stream);
  (void)hipMemsetAsync(h16, 0, (size_t)N * E * 2, stream);
  (void)hipMemsetAsync(out16, 0, (size_t)N * C * 2, stream);

  count_kernel<<<CBLK, 256, 0, stream>>>(hor_cols, gcount);
  scan_kernel<<<1, 1024, 0, stream>>>(gcount, gstart, gcursor);
  scatter_kernel<<<SBLK, 1024, 0, stream>>>(hor_rows, hor_cols, values, gcursor,
                                            packed);
  w2_gemm_kernel<<<(R * E * C + 255) / 256, 256, 0, stream>>>(comps2, bases2, W2g);
  w1_gemm_kernel<<<(N * E / 2 + 255) / 256, 256, 0, stream>>>(comps1, bases1, W1u);
  layer1_kernel<<<CB, 256, 0, stream>>>(W1u, gstart, packed, h16);
  relu_kernel<<<(N * E / 8 + 255) / 256, 256, 0, stream>>>(
      (const unsigned*)h16, bias1, h);
  layer2_kernel<<<CB, 256, 0, stream>>>(h, W2g, gstart, packed, out16);
  out_kernel<<<(N + 255) / 256, 256, 0, stream>>>(
      (const unsigned*)out16, bias2, out);
}